// Round 1
// baseline (1570.300 us; speedup 1.0000x reference)
//
#include <hip/hip_runtime.h>

#define N_TOK 4096
#define C_DIM 512
#define CI_DIM 128
#define B_DIM 4

// ---------------------------------------------------------------------------
// Kernel A: q/k/v 1x1-conv projections.  qkv[z][b][o][n] = w_z[o][:]·x[b][:][n] + b_z[o]
// grid = (64 n-tiles, B, 3 projections), block = 256
// ---------------------------------------------------------------------------
__global__ __launch_bounds__(256) void qkv_proj_kernel(
    const float* __restrict__ x,
    const float* __restrict__ wq, const float* __restrict__ bq,
    const float* __restrict__ wk, const float* __restrict__ bk,
    const float* __restrict__ wv, const float* __restrict__ bv,
    float* __restrict__ qkv)   // [3][B][CI][N]
{
    const int nt = blockIdx.x;
    const int b  = blockIdx.y;
    const int z  = blockIdx.z;
    const float* w    = (z == 0) ? wq : (z == 1) ? wk : wv;
    const float* bias = (z == 0) ? bq : (z == 1) ? bk : bv;
    float* out = qkv + (size_t)z * B_DIM * CI_DIM * N_TOK
                     + (size_t)b * CI_DIM * N_TOK;

    __shared__ float Xs[128][64];
    const int t  = threadIdx.x;
    const int n  = t & 63;
    const int o0 = __builtin_amdgcn_readfirstlane((t >> 6) * 32); // wave-uniform
    const int n0 = nt * 64;

    float acc[32];
#pragma unroll
    for (int i = 0; i < 32; ++i) acc[i] = 0.f;

    const float* xb = x + (size_t)b * C_DIM * N_TOK;

    for (int c0 = 0; c0 < C_DIM; c0 += 128) {
        __syncthreads();
        for (int idx = t; idx < 128 * 64; idx += 256) {
            int c = idx >> 6, nn = idx & 63;
            Xs[c][nn] = xb[(size_t)(c0 + c) * N_TOK + n0 + nn];
        }
        __syncthreads();
#pragma unroll 4
        for (int c = 0; c < 128; ++c) {
            float xv = Xs[c][n];
#pragma unroll
            for (int i = 0; i < 32; ++i)
                acc[i] = fmaf(w[(o0 + i) * C_DIM + c0 + c], xv, acc[i]);
        }
    }
#pragma unroll
    for (int i = 0; i < 32; ++i)
        out[(size_t)(o0 + i) * N_TOK + n0 + n] = acc[i] + bias[o0 + i];
}

// ---------------------------------------------------------------------------
// Kernel B: flash attention (no scale).  o[b][c][i] = sum_j softmax_j(q·k) v[c][j]
// grid = (128 q-tiles of 32, B), block = 256
// ---------------------------------------------------------------------------
__global__ __launch_bounds__(256) void attn_kernel(
    const float* __restrict__ qkv,   // [3][B][CI][N]
    float* __restrict__ o_out)       // [B][CI][N]
{
    const int qt = blockIdx.x;
    const int b  = blockIdx.y;
    const int q0 = qt * 32;
    const size_t bofs = (size_t)b * CI_DIM * N_TOK;
    const float* Q = qkv + bofs;
    const float* K = qkv + (size_t)B_DIM * CI_DIM * N_TOK + bofs;
    const float* V = qkv + 2 * (size_t)B_DIM * CI_DIM * N_TOK + bofs;

    __shared__ float Qs[128][33];    // padded: conflict-free final transpose write
    __shared__ float KVs[128][65];   // K then V, padded for PV-phase reads
    __shared__ float Es[32][65];     // probabilities tile
    __shared__ float mrow[32], lrow[32], srow[32];

    const int t  = threadIdx.x;
    const int qi = t >> 3;   // 0..31: this thread's query row
    const int jj = t & 7;    // 0..7 : j-offset / c-offset

    for (int idx = t; idx < 128 * 32; idx += 256) {
        int c = idx >> 5, i = idx & 31;
        Qs[c][i] = Q[(size_t)c * N_TOK + q0 + i];
    }
    if (t < 32) { mrow[t] = -1e30f; lrow[t] = 0.f; }

    float oacc[16];
#pragma unroll
    for (int m = 0; m < 16; ++m) oacc[m] = 0.f;

    for (int j0 = 0; j0 < N_TOK; j0 += 64) {
        __syncthreads();                       // prev PV done before K overwrite
        for (int idx = t; idx < 128 * 64; idx += 256) {
            int c = idx >> 6, j = idx & 63;
            KVs[c][j] = K[(size_t)c * N_TOK + j0 + j];
        }
        __syncthreads();

        // E[qi][jj + 8k] = Q[:,qi] · K[:,jj+8k]
        float e[8];
#pragma unroll
        for (int k = 0; k < 8; ++k) e[k] = 0.f;
        for (int c = 0; c < 128; ++c) {
            float qv = Qs[c][qi];
#pragma unroll
            for (int k = 0; k < 8; ++k)
                e[k] = fmaf(qv, KVs[c][jj + 8 * k], e[k]);
        }

        // online softmax: row reduce over 8 lanes (each holds 8 of 64 cols)
        float tm = e[0];
#pragma unroll
        for (int k = 1; k < 8; ++k) tm = fmaxf(tm, e[k]);
#pragma unroll
        for (int s = 1; s < 8; s <<= 1) tm = fmaxf(tm, __shfl_xor(tm, s));
        float mold = mrow[qi];
        float mnew = fmaxf(mold, tm);
        float p[8], ps = 0.f;
#pragma unroll
        for (int k = 0; k < 8; ++k) { p[k] = __expf(e[k] - mnew); ps += p[k]; }
#pragma unroll
        for (int s = 1; s < 8; s <<= 1) ps += __shfl_xor(ps, s);
        if (jj == 0) {
            float sc = __expf(mold - mnew);
            srow[qi] = sc;
            lrow[qi] = lrow[qi] * sc + ps;
            mrow[qi] = mnew;
        }
#pragma unroll
        for (int k = 0; k < 8; ++k) Es[qi][jj + 8 * k] = p[k];
        __syncthreads();                       // E reads of K done, stats ready

        for (int idx = t; idx < 128 * 64; idx += 256) {
            int c = idx >> 6, j = idx & 63;
            KVs[c][j] = V[(size_t)c * N_TOK + j0 + j];
        }
        __syncthreads();                       // V staged, Es complete

        // O[c][qi] += sum_j V[c][j] * P[qi][j],  c = jj + 8m
        float sc = srow[qi];
#pragma unroll
        for (int m = 0; m < 16; ++m) oacc[m] *= sc;
        for (int j = 0; j < 64; ++j) {
            float pv = Es[qi][j];
#pragma unroll
            for (int m = 0; m < 16; ++m)
                oacc[m] = fmaf(KVs[jj + 8 * m][j], pv, oacc[m]);
        }
    }

    // normalize, transpose through LDS (reuse Qs), coalesced store
    float linv = 1.0f / lrow[qi];
#pragma unroll
    for (int m = 0; m < 16; ++m) Qs[jj + 8 * m][qi] = oacc[m] * linv;
    __syncthreads();
    float* O = o_out + bofs;
    for (int idx = t; idx < 128 * 32; idx += 256) {
        int c = idx >> 5, i = idx & 31;
        O[(size_t)c * N_TOK + q0 + i] = Qs[c][i];
    }
}

// ---------------------------------------------------------------------------
// Kernel C: output projection + bias + residual.
// out[b][co][n] = wo[co][:]·o[b][:][n] + bo[co] + x[b][co][n]
// grid = (64 n-tiles, B, 4 co-groups of 128), block = 256
// ---------------------------------------------------------------------------
__global__ __launch_bounds__(256) void out_proj_kernel(
    const float* __restrict__ attno,  // [B][CI][N]
    const float* __restrict__ wo,     // [C][CI]
    const float* __restrict__ bo,     // [C]
    const float* __restrict__ x,      // [B][C][N]
    float* __restrict__ out)          // [B][C][N]
{
    const int nt = blockIdx.x;
    const int b  = blockIdx.y;
    const int cg = blockIdx.z;
    const int n0 = nt * 64;

    __shared__ float Os[128][64];
    const int t   = threadIdx.x;
    const int n   = t & 63;
    const int co0 = cg * 128 + __builtin_amdgcn_readfirstlane((t >> 6) * 32);

    const float* ob = attno + (size_t)b * CI_DIM * N_TOK;
    for (int idx = t; idx < 128 * 64; idx += 256) {
        int c = idx >> 6, nn = idx & 63;
        Os[c][nn] = ob[(size_t)c * N_TOK + n0 + nn];
    }
    __syncthreads();

    float acc[32];
#pragma unroll
    for (int i = 0; i < 32; ++i) acc[i] = 0.f;
#pragma unroll 4
    for (int c = 0; c < 128; ++c) {
        float ov = Os[c][n];
#pragma unroll
        for (int i = 0; i < 32; ++i)
            acc[i] = fmaf(wo[(co0 + i) * CI_DIM + c], ov, acc[i]);
    }
    const size_t base = (size_t)b * C_DIM * N_TOK;
#pragma unroll
    for (int i = 0; i < 32; ++i) {
        size_t idx = base + (size_t)(co0 + i) * N_TOK + n0 + n;
        out[idx] = acc[i] + bo[co0 + i] + x[idx];
    }
}

extern "C" void kernel_launch(void* const* d_in, const int* in_sizes, int n_in,
                              void* d_out, int out_size, void* d_ws, size_t ws_size,
                              hipStream_t stream) {
    const float* x  = (const float*)d_in[0];
    const float* wq = (const float*)d_in[1];
    const float* bq = (const float*)d_in[2];
    const float* wk = (const float*)d_in[3];
    const float* bk = (const float*)d_in[4];
    const float* wv = (const float*)d_in[5];
    const float* bv = (const float*)d_in[6];
    const float* wo = (const float*)d_in[7];
    const float* bo = (const float*)d_in[8];
    float* out = (float*)d_out;

    float* qkv   = (float*)d_ws;                               // [3][B][CI][N]
    float* attno = qkv + (size_t)3 * B_DIM * CI_DIM * N_TOK;   // [B][CI][N]

    qkv_proj_kernel<<<dim3(64, 4, 3), 256, 0, stream>>>(
        x, wq, bq, wk, bk, wv, bv, qkv);
    attn_kernel<<<dim3(128, 4), 256, 0, stream>>>(qkv, attno);
    out_proj_kernel<<<dim3(64, 4, 4), 256, 0, stream>>>(
        attno, wo, bo, x, out);
}

// Round 2
// 471.229 us; speedup vs baseline: 3.3324x; 3.3324x over previous
//
#include <hip/hip_runtime.h>

#define N_TOK 4096
#define C_DIM 512
#define CI_DIM 128
#define B_DIM 4
#define QBLK 128
#define KBLK 64

typedef unsigned short u16;
typedef unsigned int u32;
typedef unsigned long long u64;
typedef __attribute__((ext_vector_type(8))) short bf16x8;
typedef __attribute__((ext_vector_type(4))) float f32x4;
typedef __attribute__((ext_vector_type(8))) unsigned short u16x8;

__device__ __forceinline__ u16 f2bf(float f) {
    union { float f; u32 u; } v; v.f = f;
    u32 r = (v.u + 0x7fffu + ((v.u >> 16) & 1u)) >> 16;
    return (u16)r;
}

// ---------------------------------------------------------------------------
// Kernel A: q/k/v projections -> bf16.  q,k: [B][N][CI] (token-major);
// v: [B][CI][N].  grid = (64 n-tiles, B, 3), block = 256
// ---------------------------------------------------------------------------
__global__ __launch_bounds__(256) void qkv_proj_kernel(
    const float* __restrict__ x,
    const float* __restrict__ wq, const float* __restrict__ bq,
    const float* __restrict__ wk, const float* __restrict__ bk,
    const float* __restrict__ wv, const float* __restrict__ bv,
    u16* __restrict__ qT, u16* __restrict__ kT, u16* __restrict__ vB)
{
    const int nt = blockIdx.x;
    const int b  = blockIdx.y;
    const int z  = blockIdx.z;
    const float* w    = (z == 0) ? wq : (z == 1) ? wk : wv;
    const float* bias = (z == 0) ? bq : (z == 1) ? bk : bv;

    __shared__ float Xs[128][64];
    const int t  = threadIdx.x;
    const int n  = t & 63;
    const int o0 = __builtin_amdgcn_readfirstlane((t >> 6) * 32);
    const int n0 = nt * 64;

    float acc[32];
#pragma unroll
    for (int i = 0; i < 32; ++i) acc[i] = 0.f;

    const float* xb = x + (size_t)b * C_DIM * N_TOK;

    for (int c0 = 0; c0 < C_DIM; c0 += 128) {
        __syncthreads();
        for (int idx = t; idx < 128 * 64; idx += 256) {
            int c = idx >> 6, nn = idx & 63;
            Xs[c][nn] = xb[(size_t)(c0 + c) * N_TOK + n0 + nn];
        }
        __syncthreads();
#pragma unroll 4
        for (int c = 0; c < 128; ++c) {
            float xv = Xs[c][n];
#pragma unroll
            for (int i = 0; i < 32; ++i)
                acc[i] = fmaf(w[(o0 + i) * C_DIM + c0 + c], xv, acc[i]);
        }
    }

    if (z < 2) {
        u16* dst = (z == 0) ? qT : kT;
        u16 tmp[32];
#pragma unroll
        for (int i = 0; i < 32; ++i) tmp[i] = f2bf(acc[i] + bias[o0 + i]);
        u16* p = dst + ((size_t)b * N_TOK + n0 + n) * CI_DIM + o0;
#pragma unroll
        for (int g = 0; g < 4; ++g)
            *(u16x8*)&p[g * 8] = *(u16x8*)&tmp[g * 8];
    } else {
#pragma unroll
        for (int i = 0; i < 32; ++i)
            vB[((size_t)b * CI_DIM + o0 + i) * N_TOK + n0 + n] =
                f2bf(acc[i] + bias[o0 + i]);
    }
}

// ---------------------------------------------------------------------------
// Kernel B: MFMA flash attention with KV split in 2 halves.
// grid = (32 q-tiles of 128, B, 2 kv-halves), block = 256 (4 waves x 32 q)
// Writes unnormalized O partial [2][B][N][CI] f32 + m,l [2][B][N].
// ---------------------------------------------------------------------------
__global__ __launch_bounds__(256) void attn_mfma_kernel(
    const u16* __restrict__ qT,   // [B][N][CI]
    const u16* __restrict__ kT,   // [B][N][CI]
    const u16* __restrict__ vB,   // [B][CI][N]
    float* __restrict__ Opart,    // [2][B][N][CI]
    float* __restrict__ Mout,     // [2][B][N]
    float* __restrict__ Lout)     // [2][B][N]
{
    const int qb  = blockIdx.x;
    const int b   = blockIdx.y;
    const int kvh = blockIdx.z;
    const int q0  = qb * QBLK;
    const int j_beg = kvh * (N_TOK / 2);
    const int j_end = j_beg + (N_TOK / 2);

    __shared__ u16 Ks[64][136];     // K tile (also Q staging), token-major
    __shared__ u16 Vs[128][72];     // V tile, channel-major
    __shared__ u16 Ps[4][32][72];   // per-wave P tile

    const int t  = threadIdx.x;
    const int w  = t >> 6;
    const int l  = t & 63;
    const int lg = l >> 4;
    const int li = l & 15;

    const u16* qTb = qT + (size_t)b * N_TOK * CI_DIM;
    const u16* kTb = kT + (size_t)b * N_TOK * CI_DIM;
    const u16* vBb = vB + (size_t)b * CI_DIM * N_TOK;

    // ---- stage Q through Ks (2 rounds of 64 rows), preload frags to regs
    bf16x8 qf[2][4];
    for (int rnd = 0; rnd < 2; ++rnd) {
        __syncthreads();
        for (int idx = t; idx < 1024; idx += 256) {
            int r = idx >> 4, c8 = idx & 15;
            *(u16x8*)&Ks[r][c8 * 8] =
                *(const u16x8*)&qTb[(size_t)(q0 + rnd * 64 + r) * CI_DIM + c8 * 8];
        }
        __syncthreads();
        if ((w >> 1) == rnd) {
            int rb = (w & 1) * 32;
#pragma unroll
            for (int qt = 0; qt < 2; ++qt)
#pragma unroll
                for (int kc = 0; kc < 4; ++kc)
                    qf[qt][kc] = *(const bf16x8*)&Ks[rb + qt * 16 + li][kc * 32 + lg * 8];
        }
    }

    f32x4 Oacc[2][8];
#pragma unroll
    for (int qt = 0; qt < 2; ++qt)
#pragma unroll
        for (int ct = 0; ct < 8; ++ct)
#pragma unroll
            for (int r = 0; r < 4; ++r) Oacc[qt][ct][r] = 0.f;

    float mrun[2] = {-1e30f, -1e30f};
    float lrun[2] = {0.f, 0.f};

    for (int j0 = j_beg; j0 < j_end; j0 += KBLK) {
        __syncthreads();
        // stage K tile (64 tokens x 128 c) and V tile (128 c x 64 tokens)
        for (int idx = t; idx < 1024; idx += 256) {
            int r = idx >> 4, c8 = idx & 15;
            *(u16x8*)&Ks[r][c8 * 8] =
                *(const u16x8*)&kTb[(size_t)(j0 + r) * CI_DIM + c8 * 8];
        }
        for (int idx = t; idx < 1024; idx += 256) {
            int c = idx >> 3, j8 = idx & 7;
            *(u16x8*)&Vs[c][j8 * 8] =
                *(const u16x8*)&vBb[(size_t)c * N_TOK + j0 + j8 * 8];
        }
        __syncthreads();

        // ---- QK^T (swapped): S^T[j][i], per wave: 32 queries x 64 keys
        f32x4 sacc[2][4];
#pragma unroll
        for (int qt = 0; qt < 2; ++qt)
#pragma unroll
            for (int jt = 0; jt < 4; ++jt)
#pragma unroll
                for (int r = 0; r < 4; ++r) sacc[qt][jt][r] = 0.f;

#pragma unroll
        for (int jt = 0; jt < 4; ++jt) {
#pragma unroll
            for (int kc = 0; kc < 4; ++kc) {
                bf16x8 ak = *(const bf16x8*)&Ks[jt * 16 + li][kc * 32 + lg * 8];
                sacc[0][jt] = __builtin_amdgcn_mfma_f32_16x16x32_bf16(ak, qf[0][kc], sacc[0][jt], 0, 0, 0);
                sacc[1][jt] = __builtin_amdgcn_mfma_f32_16x16x32_bf16(ak, qf[1][kc], sacc[1][jt], 0, 0, 0);
            }
        }

        // ---- online softmax per query column (col = li; j spread over lg,reg)
#pragma unroll
        for (int qt = 0; qt < 2; ++qt) {
            float tmax = sacc[qt][0][0];
#pragma unroll
            for (int jt = 0; jt < 4; ++jt)
#pragma unroll
                for (int r = 0; r < 4; ++r) tmax = fmaxf(tmax, sacc[qt][jt][r]);
            tmax = fmaxf(tmax, __shfl_xor(tmax, 16));
            tmax = fmaxf(tmax, __shfl_xor(tmax, 32));

            float mold = mrun[qt];
            float mnew = fmaxf(mold, tmax);
            bool grow = mnew > mold;
            float psum = 0.f;
#pragma unroll
            for (int jt = 0; jt < 4; ++jt) {
                float p0 = __expf(sacc[qt][jt][0] - mnew);
                float p1 = __expf(sacc[qt][jt][1] - mnew);
                float p2 = __expf(sacc[qt][jt][2] - mnew);
                float p3 = __expf(sacc[qt][jt][3] - mnew);
                psum += (p0 + p1) + (p2 + p3);
                u32 lo = (u32)f2bf(p0) | ((u32)f2bf(p1) << 16);
                u32 hi = (u32)f2bf(p2) | ((u32)f2bf(p3) << 16);
                u64 pk = (u64)lo | ((u64)hi << 32);
                *(u64*)&Ps[w][qt * 16 + li][jt * 16 + lg * 4] = pk;
            }
            psum += __shfl_xor(psum, 16);
            psum += __shfl_xor(psum, 32);

            if (__any(grow)) {
                float scale = __expf(mold - mnew);
                lrun[qt] = lrun[qt] * scale + psum;
                mrun[qt] = mnew;
#pragma unroll
                for (int r = 0; r < 4; ++r) {
                    float sc_r = __shfl(scale, lg * 4 + r);
#pragma unroll
                    for (int ct = 0; ct < 8; ++ct) Oacc[qt][ct][r] *= sc_r;
                }
            } else {
                lrun[qt] += psum;
            }
        }

        // ---- PV: O^T[i][c] += P[i][j] * V^T[j][c]
#pragma unroll
        for (int ks = 0; ks < 2; ++ks) {
            bf16x8 ap0 = *(const bf16x8*)&Ps[w][li][ks * 32 + lg * 8];
            bf16x8 ap1 = *(const bf16x8*)&Ps[w][16 + li][ks * 32 + lg * 8];
#pragma unroll
            for (int ct = 0; ct < 8; ++ct) {
                bf16x8 bv = *(const bf16x8*)&Vs[ct * 16 + li][ks * 32 + lg * 8];
                Oacc[0][ct] = __builtin_amdgcn_mfma_f32_16x16x32_bf16(ap0, bv, Oacc[0][ct], 0, 0, 0);
                Oacc[1][ct] = __builtin_amdgcn_mfma_f32_16x16x32_bf16(ap1, bv, Oacc[1][ct], 0, 0, 0);
            }
        }
    }

    // ---- epilogue: write m/l and unnormalized O partial
    const size_t mlbase = ((size_t)kvh * B_DIM + b) * N_TOK + q0 + w * 32;
    if (lg == 0) {
#pragma unroll
        for (int qt = 0; qt < 2; ++qt) {
            Mout[mlbase + qt * 16 + li] = mrun[qt];
            Lout[mlbase + qt * 16 + li] = lrun[qt];
        }
    }
    float* Ob = Opart + mlbase * CI_DIM;
#pragma unroll
    for (int qt = 0; qt < 2; ++qt)
#pragma unroll
        for (int ct = 0; ct < 8; ++ct)
#pragma unroll
            for (int r = 0; r < 4; ++r)
                Ob[(size_t)(qt * 16 + lg * 4 + r) * CI_DIM + ct * 16 + li] = Oacc[qt][ct][r];
}

// ---------------------------------------------------------------------------
// Kernel C: merge the 2 KV-half partials -> attno [B][CI][N] f32
// grid = (64 q-tiles of 64, B), block = 256
// ---------------------------------------------------------------------------
__global__ __launch_bounds__(256) void attn_merge_kernel(
    const float* __restrict__ Opart, const float* __restrict__ Mout,
    const float* __restrict__ Lout, float* __restrict__ attno)
{
    const int qb = blockIdx.x;
    const int b  = blockIdx.y;
    const int t  = threadIdx.x;
    const int i  = qb * 64 + (t & 63);
    const int c0 = (t >> 6) * 32;

    const size_t n0 = (size_t)b * N_TOK + i;
    const size_t n1 = (size_t)(B_DIM + b) * N_TOK + i;
    float m0 = Mout[n0], m1 = Mout[n1];
    float l0 = Lout[n0], l1 = Lout[n1];
    float m  = fmaxf(m0, m1);
    float s0 = __expf(m0 - m), s1 = __expf(m1 - m);
    float linv = 1.f / (l0 * s0 + l1 * s1);
    s0 *= linv; s1 *= linv;

    const float* O0 = Opart + n0 * CI_DIM;
    const float* O1 = Opart + n1 * CI_DIM;
    float* ab = attno + (size_t)b * CI_DIM * N_TOK;
#pragma unroll 8
    for (int c = c0; c < c0 + 32; ++c)
        ab[(size_t)c * N_TOK + i] = O0[c] * s0 + O1[c] * s1;
}

// ---------------------------------------------------------------------------
// Kernel D: output projection + bias + residual (unchanged, fp32)
// ---------------------------------------------------------------------------
__global__ __launch_bounds__(256) void out_proj_kernel(
    const float* __restrict__ attno,  // [B][CI][N]
    const float* __restrict__ wo,     // [C][CI]
    const float* __restrict__ bo,     // [C]
    const float* __restrict__ x,      // [B][C][N]
    float* __restrict__ out)          // [B][C][N]
{
    const int nt = blockIdx.x;
    const int b  = blockIdx.y;
    const int cg = blockIdx.z;
    const int n0 = nt * 64;

    __shared__ float Os[128][64];
    const int t   = threadIdx.x;
    const int n   = t & 63;
    const int co0 = cg * 128 + __builtin_amdgcn_readfirstlane((t >> 6) * 32);

    const float* ob = attno + (size_t)b * CI_DIM * N_TOK;
    for (int idx = t; idx < 128 * 64; idx += 256) {
        int c = idx >> 6, nn = idx & 63;
        Os[c][nn] = ob[(size_t)c * N_TOK + n0 + nn];
    }
    __syncthreads();

    float acc[32];
#pragma unroll
    for (int i = 0; i < 32; ++i) acc[i] = 0.f;
#pragma unroll 4
    for (int c = 0; c < 128; ++c) {
        float ov = Os[c][n];
#pragma unroll
        for (int i = 0; i < 32; ++i)
            acc[i] = fmaf(wo[(co0 + i) * CI_DIM + c], ov, acc[i]);
    }
    const size_t base = (size_t)b * C_DIM * N_TOK;
#pragma unroll
    for (int i = 0; i < 32; ++i) {
        size_t idx = base + (size_t)(co0 + i) * N_TOK + n0 + n;
        out[idx] = acc[i] + bo[co0 + i] + x[idx];
    }
}

extern "C" void kernel_launch(void* const* d_in, const int* in_sizes, int n_in,
                              void* d_out, int out_size, void* d_ws, size_t ws_size,
                              hipStream_t stream) {
    const float* x  = (const float*)d_in[0];
    const float* wq = (const float*)d_in[1];
    const float* bq = (const float*)d_in[2];
    const float* wk = (const float*)d_in[3];
    const float* bk = (const float*)d_in[4];
    const float* wv = (const float*)d_in[5];
    const float* bv = (const float*)d_in[6];
    const float* wo = (const float*)d_in[7];
    const float* bo = (const float*)d_in[8];
    float* out = (float*)d_out;

    // workspace layout (bytes):
    //   [0,  4M)  qT bf16   [B][N][CI]     -+ aliased later by attno (8 MB f32)
    //   [4M, 8M)  kT bf16   [B][N][CI]     -+
    //   [8M,12M)  vB bf16   [B][CI][N]
    //   [12M,28M) Opart f32 [2][B][N][CI]
    //   [28M,28M+128K)      Mout f32 [2][B][N]
    //   [28M+128K,28M+256K) Lout f32 [2][B][N]
    char* ws = (char*)d_ws;
    const size_t MB = 1024 * 1024;
    u16*   qT    = (u16*)(ws);
    u16*   kT    = (u16*)(ws + 4 * MB);
    u16*   vB    = (u16*)(ws + 8 * MB);
    float* Opart = (float*)(ws + 12 * MB);
    float* Mout  = (float*)(ws + 28 * MB);
    float* Lout  = (float*)(ws + 28 * MB + 128 * 1024);
    float* attno = (float*)(ws);  // aliases qT/kT after attn completes

    qkv_proj_kernel<<<dim3(64, 4, 3), 256, 0, stream>>>(
        x, wq, bq, wk, bk, wv, bv, qT, kT, vB);
    attn_mfma_kernel<<<dim3(32, 4, 2), 256, 0, stream>>>(
        qT, kT, vB, Opart, Mout, Lout);
    attn_merge_kernel<<<dim3(64, 4), 256, 0, stream>>>(
        Opart, Mout, Lout, attno);
    out_proj_kernel<<<dim3(64, 4, 4), 256, 0, stream>>>(
        attno, wo, bo, x, out);
}

// Round 3
// 230.262 us; speedup vs baseline: 6.8196x; 2.0465x over previous
//
#include <hip/hip_runtime.h>

#define N_TOK 4096
#define C_DIM 512
#define CI_DIM 128
#define B_DIM 4
#define QBLK 128
#define KBLK 64

typedef unsigned short u16;
typedef unsigned int u32;
typedef unsigned long long u64;
typedef __attribute__((ext_vector_type(8))) short bf16x8;
typedef __attribute__((ext_vector_type(4))) float f32x4;
typedef __attribute__((ext_vector_type(8))) unsigned short u16x8;
typedef __attribute__((ext_vector_type(4))) float float4v;

__device__ __forceinline__ u16 f2bf(float f) {
    union { float f; u32 u; } v; v.f = f;
    u32 r = (v.u + 0x7fffu + ((v.u >> 16) & 1u)) >> 16;
    return (u16)r;
}

// ---------------------------------------------------------------------------
// Prepass 1: transpose+convert x f32 [B][C][N] -> xT bf16 [B][N][C]
// grid = (64 n-tiles, 8 c-tiles, B), block = 256
// ---------------------------------------------------------------------------
__global__ __launch_bounds__(256) void xpose_kernel(
    const float* __restrict__ x, u16* __restrict__ xT)
{
    const int n0 = blockIdx.x * 64;
    const int c0 = blockIdx.y * 64;
    const int b  = blockIdx.z;
    __shared__ u16 Ts[64][72];
    const int t = threadIdx.x;

    const float* xb = x + (size_t)b * C_DIM * N_TOK;
    for (int idx = t; idx < 4096; idx += 256) {
        int c = idx >> 6, n = idx & 63;
        Ts[n][c] = f2bf(xb[(size_t)(c0 + c) * N_TOK + n0 + n]);
    }
    __syncthreads();
    u16* xTb = xT + (size_t)b * N_TOK * C_DIM;
    for (int idx = t; idx < 512; idx += 256) {
        int n = idx >> 3, c8 = idx & 7;
        *(u16x8*)&xTb[(size_t)(n0 + n) * C_DIM + c0 + c8 * 8] =
            *(u16x8*)&Ts[n][c8 * 8];
    }
}

// ---------------------------------------------------------------------------
// Prepass 2: convert weights to bf16 (layouts unchanged).
// grid = (32, 4), block = 256; z selects which matrix (each 65536 elems)
// ---------------------------------------------------------------------------
__global__ __launch_bounds__(256) void wconv_kernel(
    const float* __restrict__ wq, const float* __restrict__ wk,
    const float* __restrict__ wv, const float* __restrict__ wo,
    u16* __restrict__ wqB, u16* __restrict__ wkB,
    u16* __restrict__ wvB, u16* __restrict__ woB)
{
    const int z = blockIdx.y;
    const float* src = (z == 0) ? wq : (z == 1) ? wk : (z == 2) ? wv : wo;
    u16* dst = (z == 0) ? wqB : (z == 1) ? wkB : (z == 2) ? wvB : woB;
    const int i0 = (blockIdx.x * 256 + threadIdx.x) * 8;
    float4v a = *(const float4v*)&src[i0];
    float4v b = *(const float4v*)&src[i0 + 4];
    u16x8 o;
    o[0] = f2bf(a[0]); o[1] = f2bf(a[1]); o[2] = f2bf(a[2]); o[3] = f2bf(a[3]);
    o[4] = f2bf(b[0]); o[5] = f2bf(b[1]); o[6] = f2bf(b[2]); o[7] = f2bf(b[3]);
    *(u16x8*)&dst[i0] = o;
}

// ---------------------------------------------------------------------------
// Kernel A: q/k/v projections via MFMA.
// q,k -> [B][N][CI] token-major; v -> [B][CI][N].
// grid = (32 n-tiles of 128, B, 3), block = 256 (4 waves, each a 128x32 stripe)
// ---------------------------------------------------------------------------
__global__ __launch_bounds__(256) void qkv_gemm_kernel(
    const u16* __restrict__ xT,   // [B][N][C] bf16
    const u16* __restrict__ wqB, const u16* __restrict__ wkB,
    const u16* __restrict__ wvB,
    const float* __restrict__ bq, const float* __restrict__ bk,
    const float* __restrict__ bv,
    u16* __restrict__ qT, u16* __restrict__ kT, u16* __restrict__ vB)
{
    const int n0 = blockIdx.x * 128;
    const int b  = blockIdx.y;
    const int z  = blockIdx.z;
    const u16* wz = (z == 0) ? wqB : (z == 1) ? wkB : wvB;
    const float* bias = (z == 0) ? bq : (z == 1) ? bk : bv;

    const int t  = threadIdx.x;
    const int w  = t >> 6;
    const int l  = t & 63;
    const int lg = l >> 4;
    const int li = l & 15;
    const int cb = w * 32;             // this wave's 32-col stripe

    const u16* xTb = xT + (size_t)b * N_TOK * C_DIM;

    // A = rows matrix, B = cols matrix (both row-major over k, K=C_DIM)
    const u16* Amat; const u16* Bmat; int arow0, brow0;
    if (z < 2) { Amat = xTb; arow0 = n0; Bmat = wz;  brow0 = 0; }
    else       { Amat = wz;  arow0 = 0;  Bmat = xTb; brow0 = n0; }

    f32x4 acc[8][2];
#pragma unroll
    for (int m = 0; m < 8; ++m)
#pragma unroll
        for (int j = 0; j < 2; ++j)
#pragma unroll
            for (int r = 0; r < 4; ++r) acc[m][j][r] = 0.f;

    const u16* Abase = Amat + (size_t)(arow0 + li) * C_DIM + lg * 8;
    const u16* Bbase = Bmat + (size_t)(brow0 + cb + li) * C_DIM + lg * 8;

#pragma unroll 2
    for (int kk = 0; kk < 16; ++kk) {
        bf16x8 af[8], bfv[2];
#pragma unroll
        for (int m = 0; m < 8; ++m)
            af[m] = *(const bf16x8*)&Abase[(size_t)(m * 16) * C_DIM + kk * 32];
#pragma unroll
        for (int j = 0; j < 2; ++j)
            bfv[j] = *(const bf16x8*)&Bbase[(size_t)(j * 16) * C_DIM + kk * 32];
#pragma unroll
        for (int m = 0; m < 8; ++m)
#pragma unroll
            for (int j = 0; j < 2; ++j)
                acc[m][j] = __builtin_amdgcn_mfma_f32_16x16x32_bf16(
                    af[m], bfv[j], acc[m][j], 0, 0, 0);
    }

    if (z < 2) {
        // D[n][o]: row n = n0+m*16+lg*4+r, col o = cb+j*16+li
        u16* dst = ((z == 0) ? qT : kT) + (size_t)b * N_TOK * CI_DIM;
#pragma unroll
        for (int j = 0; j < 2; ++j) {
            float bia = bias[cb + j * 16 + li];
#pragma unroll
            for (int m = 0; m < 8; ++m)
#pragma unroll
                for (int r = 0; r < 4; ++r)
                    dst[(size_t)(n0 + m * 16 + lg * 4 + r) * CI_DIM + cb + j * 16 + li] =
                        f2bf(acc[m][j][r] + bia);
        }
    } else {
        // D[o][n]: row o = m*16+lg*4+r, col n = n0+cb+j*16+li
        u16* dst = vB + (size_t)b * CI_DIM * N_TOK;
#pragma unroll
        for (int m = 0; m < 8; ++m)
#pragma unroll
            for (int r = 0; r < 4; ++r) {
                int o = m * 16 + lg * 4 + r;
                float bia = bias[o];
#pragma unroll
                for (int j = 0; j < 2; ++j)
                    dst[(size_t)o * N_TOK + n0 + cb + j * 16 + li] =
                        f2bf(acc[m][j][r] + bia);
            }
    }
}

// ---------------------------------------------------------------------------
// Kernel B: MFMA flash attention with KV split in 2 halves. (unchanged)
// ---------------------------------------------------------------------------
__global__ __launch_bounds__(256) void attn_mfma_kernel(
    const u16* __restrict__ qT,   // [B][N][CI]
    const u16* __restrict__ kT,   // [B][N][CI]
    const u16* __restrict__ vB,   // [B][CI][N]
    float* __restrict__ Opart,    // [2][B][N][CI]
    float* __restrict__ Mout,     // [2][B][N]
    float* __restrict__ Lout)     // [2][B][N]
{
    const int qb  = blockIdx.x;
    const int b   = blockIdx.y;
    const int kvh = blockIdx.z;
    const int q0  = qb * QBLK;
    const int j_beg = kvh * (N_TOK / 2);
    const int j_end = j_beg + (N_TOK / 2);

    __shared__ u16 Ks[64][136];
    __shared__ u16 Vs[128][72];
    __shared__ u16 Ps[4][32][72];

    const int t  = threadIdx.x;
    const int w  = t >> 6;
    const int l  = t & 63;
    const int lg = l >> 4;
    const int li = l & 15;

    const u16* qTb = qT + (size_t)b * N_TOK * CI_DIM;
    const u16* kTb = kT + (size_t)b * N_TOK * CI_DIM;
    const u16* vBb = vB + (size_t)b * CI_DIM * N_TOK;

    bf16x8 qf[2][4];
    for (int rnd = 0; rnd < 2; ++rnd) {
        __syncthreads();
        for (int idx = t; idx < 1024; idx += 256) {
            int r = idx >> 4, c8 = idx & 15;
            *(u16x8*)&Ks[r][c8 * 8] =
                *(const u16x8*)&qTb[(size_t)(q0 + rnd * 64 + r) * CI_DIM + c8 * 8];
        }
        __syncthreads();
        if ((w >> 1) == rnd) {
            int rb = (w & 1) * 32;
#pragma unroll
            for (int qt = 0; qt < 2; ++qt)
#pragma unroll
                for (int kc = 0; kc < 4; ++kc)
                    qf[qt][kc] = *(const bf16x8*)&Ks[rb + qt * 16 + li][kc * 32 + lg * 8];
        }
    }

    f32x4 Oacc[2][8];
#pragma unroll
    for (int qt = 0; qt < 2; ++qt)
#pragma unroll
        for (int ct = 0; ct < 8; ++ct)
#pragma unroll
            for (int r = 0; r < 4; ++r) Oacc[qt][ct][r] = 0.f;

    float mrun[2] = {-1e30f, -1e30f};
    float lrun[2] = {0.f, 0.f};

    for (int j0 = j_beg; j0 < j_end; j0 += KBLK) {
        __syncthreads();
        for (int idx = t; idx < 1024; idx += 256) {
            int r = idx >> 4, c8 = idx & 15;
            *(u16x8*)&Ks[r][c8 * 8] =
                *(const u16x8*)&kTb[(size_t)(j0 + r) * CI_DIM + c8 * 8];
        }
        for (int idx = t; idx < 1024; idx += 256) {
            int c = idx >> 3, j8 = idx & 7;
            *(u16x8*)&Vs[c][j8 * 8] =
                *(const u16x8*)&vBb[(size_t)c * N_TOK + j0 + j8 * 8];
        }
        __syncthreads();

        f32x4 sacc[2][4];
#pragma unroll
        for (int qt = 0; qt < 2; ++qt)
#pragma unroll
            for (int jt = 0; jt < 4; ++jt)
#pragma unroll
                for (int r = 0; r < 4; ++r) sacc[qt][jt][r] = 0.f;

#pragma unroll
        for (int jt = 0; jt < 4; ++jt) {
#pragma unroll
            for (int kc = 0; kc < 4; ++kc) {
                bf16x8 ak = *(const bf16x8*)&Ks[jt * 16 + li][kc * 32 + lg * 8];
                sacc[0][jt] = __builtin_amdgcn_mfma_f32_16x16x32_bf16(ak, qf[0][kc], sacc[0][jt], 0, 0, 0);
                sacc[1][jt] = __builtin_amdgcn_mfma_f32_16x16x32_bf16(ak, qf[1][kc], sacc[1][jt], 0, 0, 0);
            }
        }

#pragma unroll
        for (int qt = 0; qt < 2; ++qt) {
            float tmax = sacc[qt][0][0];
#pragma unroll
            for (int jt = 0; jt < 4; ++jt)
#pragma unroll
                for (int r = 0; r < 4; ++r) tmax = fmaxf(tmax, sacc[qt][jt][r]);
            tmax = fmaxf(tmax, __shfl_xor(tmax, 16));
            tmax = fmaxf(tmax, __shfl_xor(tmax, 32));

            float mold = mrun[qt];
            float mnew = fmaxf(mold, tmax);
            bool grow = mnew > mold;
            float psum = 0.f;
#pragma unroll
            for (int jt = 0; jt < 4; ++jt) {
                float p0 = __expf(sacc[qt][jt][0] - mnew);
                float p1 = __expf(sacc[qt][jt][1] - mnew);
                float p2 = __expf(sacc[qt][jt][2] - mnew);
                float p3 = __expf(sacc[qt][jt][3] - mnew);
                psum += (p0 + p1) + (p2 + p3);
                u32 lo = (u32)f2bf(p0) | ((u32)f2bf(p1) << 16);
                u32 hi = (u32)f2bf(p2) | ((u32)f2bf(p3) << 16);
                u64 pk = (u64)lo | ((u64)hi << 32);
                *(u64*)&Ps[w][qt * 16 + li][jt * 16 + lg * 4] = pk;
            }
            psum += __shfl_xor(psum, 16);
            psum += __shfl_xor(psum, 32);

            if (__any(grow)) {
                float scale = __expf(mold - mnew);
                lrun[qt] = lrun[qt] * scale + psum;
                mrun[qt] = mnew;
#pragma unroll
                for (int r = 0; r < 4; ++r) {
                    float sc_r = __shfl(scale, lg * 4 + r);
#pragma unroll
                    for (int ct = 0; ct < 8; ++ct) Oacc[qt][ct][r] *= sc_r;
                }
            } else {
                lrun[qt] += psum;
            }
        }

#pragma unroll
        for (int ks = 0; ks < 2; ++ks) {
            bf16x8 ap0 = *(const bf16x8*)&Ps[w][li][ks * 32 + lg * 8];
            bf16x8 ap1 = *(const bf16x8*)&Ps[w][16 + li][ks * 32 + lg * 8];
#pragma unroll
            for (int ct = 0; ct < 8; ++ct) {
                bf16x8 bv = *(const bf16x8*)&Vs[ct * 16 + li][ks * 32 + lg * 8];
                Oacc[0][ct] = __builtin_amdgcn_mfma_f32_16x16x32_bf16(ap0, bv, Oacc[0][ct], 0, 0, 0);
                Oacc[1][ct] = __builtin_amdgcn_mfma_f32_16x16x32_bf16(ap1, bv, Oacc[1][ct], 0, 0, 0);
            }
        }
    }

    const size_t mlbase = ((size_t)kvh * B_DIM + b) * N_TOK + q0 + w * 32;
    if (lg == 0) {
#pragma unroll
        for (int qt = 0; qt < 2; ++qt) {
            Mout[mlbase + qt * 16 + li] = mrun[qt];
            Lout[mlbase + qt * 16 + li] = lrun[qt];
        }
    }
    float* Ob = Opart + mlbase * CI_DIM;
#pragma unroll
    for (int qt = 0; qt < 2; ++qt)
#pragma unroll
        for (int ct = 0; ct < 8; ++ct)
#pragma unroll
            for (int r = 0; r < 4; ++r)
                Ob[(size_t)(qt * 16 + lg * 4 + r) * CI_DIM + ct * 16 + li] = Oacc[qt][ct][r];
}

// ---------------------------------------------------------------------------
// Kernel C: merge the 2 KV-half partials -> attnoB bf16 [B][N][CI] token-major
// grid = (64 q-tiles of 64, B), block = 256
// ---------------------------------------------------------------------------
__global__ __launch_bounds__(256) void attn_merge_kernel(
    const float* __restrict__ Opart, const float* __restrict__ Mout,
    const float* __restrict__ Lout, u16* __restrict__ attnoB)
{
    const int qb = blockIdx.x;
    const int b  = blockIdx.y;
    const int t  = threadIdx.x;
    const int i  = qb * 64 + (t & 63);
    const int c0 = (t >> 6) * 32;

    const size_t n0 = (size_t)b * N_TOK + i;
    const size_t n1 = (size_t)(B_DIM + b) * N_TOK + i;
    float m0 = Mout[n0], m1 = Mout[n1];
    float l0 = Lout[n0], l1 = Lout[n1];
    float m  = fmaxf(m0, m1);
    float s0 = __expf(m0 - m), s1 = __expf(m1 - m);
    float linv = 1.f / (l0 * s0 + l1 * s1);
    s0 *= linv; s1 *= linv;

    const float* O0 = Opart + n0 * CI_DIM;
    const float* O1 = Opart + n1 * CI_DIM;
    u16* ab = attnoB + n0 * CI_DIM;
#pragma unroll
    for (int g = 0; g < 4; ++g) {
        u16x8 ov;
#pragma unroll
        for (int e = 0; e < 8; ++e) {
            int c = c0 + g * 8 + e;
            ov[e] = f2bf(O0[c] * s0 + O1[c] * s1);
        }
        *(u16x8*)&ab[c0 + g * 8] = ov;
    }
}

// ---------------------------------------------------------------------------
// Kernel D: output projection via MFMA + bias + residual, fp32 out.
// grid = (64 n-tiles of 64, B), block = 256 (4 waves; wave w -> co rows w*128..)
// ---------------------------------------------------------------------------
__global__ __launch_bounds__(256) void out_gemm_kernel(
    const u16* __restrict__ attnoB,  // [B][N][CI] bf16
    const u16* __restrict__ woB,     // [C][CI] bf16
    const float* __restrict__ bo,    // [C]
    const float* __restrict__ x,     // [B][C][N]
    float* __restrict__ out)         // [B][C][N]
{
    const int n0 = blockIdx.x * 64;
    const int b  = blockIdx.y;
    const int t  = threadIdx.x;
    const int w  = t >> 6;
    const int l  = t & 63;
    const int lg = l >> 4;
    const int li = l & 15;
    const int co0 = w * 128;

    const u16* ab = attnoB + (size_t)b * N_TOK * CI_DIM;

    f32x4 acc[8][4];
#pragma unroll
    for (int m = 0; m < 8; ++m)
#pragma unroll
        for (int j = 0; j < 4; ++j)
#pragma unroll
            for (int r = 0; r < 4; ++r) acc[m][j][r] = 0.f;

    const u16* Abase = woB + (size_t)(co0 + li) * CI_DIM + lg * 8;
    const u16* Bbase = ab + (size_t)(n0 + li) * CI_DIM + lg * 8;

#pragma unroll
    for (int kk = 0; kk < 4; ++kk) {
        bf16x8 af[8], bfv[4];
#pragma unroll
        for (int m = 0; m < 8; ++m)
            af[m] = *(const bf16x8*)&Abase[(size_t)(m * 16) * CI_DIM + kk * 32];
#pragma unroll
        for (int j = 0; j < 4; ++j)
            bfv[j] = *(const bf16x8*)&Bbase[(size_t)(j * 16) * CI_DIM + kk * 32];
#pragma unroll
        for (int m = 0; m < 8; ++m)
#pragma unroll
            for (int j = 0; j < 4; ++j)
                acc[m][j] = __builtin_amdgcn_mfma_f32_16x16x32_bf16(
                    af[m], bfv[j], acc[m][j], 0, 0, 0);
    }

    const size_t base = (size_t)b * C_DIM * N_TOK;
#pragma unroll
    for (int m = 0; m < 8; ++m)
#pragma unroll
        for (int r = 0; r < 4; ++r) {
            int co = co0 + m * 16 + lg * 4 + r;
            float bia = bo[co];
#pragma unroll
            for (int j = 0; j < 4; ++j) {
                size_t idx = base + (size_t)co * N_TOK + n0 + j * 16 + li;
                out[idx] = acc[m][j][r] + bia + x[idx];
            }
        }
}

extern "C" void kernel_launch(void* const* d_in, const int* in_sizes, int n_in,
                              void* d_out, int out_size, void* d_ws, size_t ws_size,
                              hipStream_t stream) {
    const float* x  = (const float*)d_in[0];
    const float* wq = (const float*)d_in[1];
    const float* bq = (const float*)d_in[2];
    const float* wk = (const float*)d_in[3];
    const float* bk = (const float*)d_in[4];
    const float* wv = (const float*)d_in[5];
    const float* bv = (const float*)d_in[6];
    const float* wo = (const float*)d_in[7];
    const float* bo = (const float*)d_in[8];
    float* out = (float*)d_out;

    // workspace layout (bytes):
    //  [0,16M)        xT bf16 [B][N][C]  -- dead after qkv_gemm; reused as Opart
    //  [16M,16.5M)    wqB/wkB/wvB/woB bf16 (128K each)
    //  [16.5M,20.5M)  qT bf16 [B][N][CI]
    //  [20.5M,24.5M)  kT bf16 [B][N][CI]
    //  [24.5M,28.5M)  vB bf16 [B][CI][N]
    //  [28.5M,+256K)  Mout/Lout f32 [2][B][N]
    //  [28.75M,32.75M) attnoB bf16 [B][N][CI]
    char* ws = (char*)d_ws;
    const size_t MB = 1024 * 1024;
    u16*   xT    = (u16*)(ws);
    float* Opart = (float*)(ws);                 // aliases xT (16 MB, exact)
    u16*   wqB   = (u16*)(ws + 16 * MB);
    u16*   wkB   = (u16*)(ws + 16 * MB + 128 * 1024);
    u16*   wvB   = (u16*)(ws + 16 * MB + 256 * 1024);
    u16*   woB   = (u16*)(ws + 16 * MB + 384 * 1024);
    u16*   qT    = (u16*)(ws + 16 * MB + 512 * 1024);
    u16*   kT    = (u16*)(ws + 20 * MB + 512 * 1024);
    u16*   vB    = (u16*)(ws + 24 * MB + 512 * 1024);
    float* Mout  = (float*)(ws + 28 * MB + 512 * 1024);
    float* Lout  = (float*)(ws + 28 * MB + 640 * 1024);
    u16*  attnoB = (u16*)(ws + 28 * MB + 768 * 1024);

    xpose_kernel<<<dim3(64, 8, 4), 256, 0, stream>>>(x, xT);
    wconv_kernel<<<dim3(32, 4), 256, 0, stream>>>(
        wq, wk, wv, wo, wqB, wkB, wvB, woB);
    qkv_gemm_kernel<<<dim3(32, 4, 3), 256, 0, stream>>>(
        xT, wqB, wkB, wvB, bq, bk, bv, qT, kT, vB);
    attn_mfma_kernel<<<dim3(32, 4, 2), 256, 0, stream>>>(
        qT, kT, vB, Opart, Mout, Lout);
    attn_merge_kernel<<<dim3(64, 4), 256, 0, stream>>>(
        Opart, Mout, Lout, attnoB);
    out_gemm_kernel<<<dim3(64, 4), 256, 0, stream>>>(
        attnoB, woB, bo, x, out);
}

// Round 4
// 201.154 us; speedup vs baseline: 7.8064x; 1.1447x over previous
//
#include <hip/hip_runtime.h>

#define N_TOK 4096
#define C_DIM 512
#define CI_DIM 128
#define B_DIM 4
#define KVSPLIT 4

typedef unsigned short u16;
typedef unsigned int u32;
typedef unsigned long long u64;
typedef __attribute__((ext_vector_type(8))) short bf16x8;
typedef __attribute__((ext_vector_type(4))) float f32x4;
typedef __attribute__((ext_vector_type(8))) unsigned short u16x8;
typedef __attribute__((ext_vector_type(4))) float float4v;

__device__ __forceinline__ u16 f2bf(float f) {
    union { float f; u32 u; } v; v.f = f;
    u32 r = (v.u + 0x7fffu + ((v.u >> 16) & 1u)) >> 16;
    return (u16)r;
}
__device__ __forceinline__ float bf2f(u16 h) {
    union { u32 u; float f; } v; v.u = (u32)h << 16;
    return v.f;
}
__device__ __forceinline__ u32 cvt_pk_bf16(float a, float b) {
    u32 r;
    asm("v_cvt_pk_bf16_f32 %0, %1, %2" : "=v"(r) : "v"(a), "v"(b));
    return r;
}

// ---------------------------------------------------------------------------
// Prepass 1: transpose+convert x f32 [B][C][N] -> xT bf16 [B][N][C]
// ---------------------------------------------------------------------------
__global__ __launch_bounds__(256) void xpose_kernel(
    const float* __restrict__ x, u16* __restrict__ xT)
{
    const int n0 = blockIdx.x * 64;
    const int c0 = blockIdx.y * 64;
    const int b  = blockIdx.z;
    __shared__ u16 Ts[64][72];
    const int t = threadIdx.x;

    const float* xb = x + (size_t)b * C_DIM * N_TOK;
    for (int idx = t; idx < 4096; idx += 256) {
        int c = idx >> 6, n = idx & 63;
        Ts[n][c] = f2bf(xb[(size_t)(c0 + c) * N_TOK + n0 + n]);
    }
    __syncthreads();
    u16* xTb = xT + (size_t)b * N_TOK * C_DIM;
    for (int idx = t; idx < 512; idx += 256) {
        int n = idx >> 3, c8 = idx & 7;
        *(u16x8*)&xTb[(size_t)(n0 + n) * C_DIM + c0 + c8 * 8] =
            *(u16x8*)&Ts[n][c8 * 8];
    }
}

// ---------------------------------------------------------------------------
// Prepass 2: convert weights to bf16 (layouts unchanged).
// ---------------------------------------------------------------------------
__global__ __launch_bounds__(256) void wconv_kernel(
    const float* __restrict__ wq, const float* __restrict__ wk,
    const float* __restrict__ wv, const float* __restrict__ wo,
    u16* __restrict__ wqB, u16* __restrict__ wkB,
    u16* __restrict__ wvB, u16* __restrict__ woB)
{
    const int z = blockIdx.y;
    const float* src = (z == 0) ? wq : (z == 1) ? wk : (z == 2) ? wv : wo;
    u16* dst = (z == 0) ? wqB : (z == 1) ? wkB : (z == 2) ? wvB : woB;
    const int i0 = (blockIdx.x * 256 + threadIdx.x) * 8;
    float4v a = *(const float4v*)&src[i0];
    float4v b = *(const float4v*)&src[i0 + 4];
    u16x8 o;
    o[0] = f2bf(a[0]); o[1] = f2bf(a[1]); o[2] = f2bf(a[2]); o[3] = f2bf(a[3]);
    o[4] = f2bf(b[0]); o[5] = f2bf(b[1]); o[6] = f2bf(b[2]); o[7] = f2bf(b[3]);
    *(u16x8*)&dst[i0] = o;
}

// ---------------------------------------------------------------------------
// Kernel A: q/k/v projections via MFMA.
// q,k -> [B][N][CI] token-major; v -> [B][CI][N].
// ---------------------------------------------------------------------------
__global__ __launch_bounds__(256) void qkv_gemm_kernel(
    const u16* __restrict__ xT,
    const u16* __restrict__ wqB, const u16* __restrict__ wkB,
    const u16* __restrict__ wvB,
    const float* __restrict__ bq, const float* __restrict__ bk,
    const float* __restrict__ bv,
    u16* __restrict__ qT, u16* __restrict__ kT, u16* __restrict__ vB)
{
    const int n0 = blockIdx.x * 128;
    const int b  = blockIdx.y;
    const int z  = blockIdx.z;
    const u16* wz = (z == 0) ? wqB : (z == 1) ? wkB : wvB;
    const float* bias = (z == 0) ? bq : (z == 1) ? bk : bv;

    const int t  = threadIdx.x;
    const int w  = t >> 6;
    const int l  = t & 63;
    const int lg = l >> 4;
    const int li = l & 15;
    const int cb = w * 32;

    const u16* xTb = xT + (size_t)b * N_TOK * C_DIM;

    const u16* Amat; const u16* Bmat; int arow0, brow0;
    if (z < 2) { Amat = xTb; arow0 = n0; Bmat = wz;  brow0 = 0; }
    else       { Amat = wz;  arow0 = 0;  Bmat = xTb; brow0 = n0; }

    f32x4 acc[8][2];
#pragma unroll
    for (int m = 0; m < 8; ++m)
#pragma unroll
        for (int j = 0; j < 2; ++j)
#pragma unroll
            for (int r = 0; r < 4; ++r) acc[m][j][r] = 0.f;

    const u16* Abase = Amat + (size_t)(arow0 + li) * C_DIM + lg * 8;
    const u16* Bbase = Bmat + (size_t)(brow0 + cb + li) * C_DIM + lg * 8;

#pragma unroll 2
    for (int kk = 0; kk < 16; ++kk) {
        bf16x8 af[8], bfv[2];
#pragma unroll
        for (int m = 0; m < 8; ++m)
            af[m] = *(const bf16x8*)&Abase[(size_t)(m * 16) * C_DIM + kk * 32];
#pragma unroll
        for (int j = 0; j < 2; ++j)
            bfv[j] = *(const bf16x8*)&Bbase[(size_t)(j * 16) * C_DIM + kk * 32];
#pragma unroll
        for (int m = 0; m < 8; ++m)
#pragma unroll
            for (int j = 0; j < 2; ++j)
                acc[m][j] = __builtin_amdgcn_mfma_f32_16x16x32_bf16(
                    af[m], bfv[j], acc[m][j], 0, 0, 0);
    }

    if (z < 2) {
        u16* dst = ((z == 0) ? qT : kT) + (size_t)b * N_TOK * CI_DIM;
#pragma unroll
        for (int j = 0; j < 2; ++j) {
            float bia = bias[cb + j * 16 + li];
#pragma unroll
            for (int m = 0; m < 8; ++m)
#pragma unroll
                for (int r = 0; r < 4; ++r)
                    dst[(size_t)(n0 + m * 16 + lg * 4 + r) * CI_DIM + cb + j * 16 + li] =
                        f2bf(acc[m][j][r] + bia);
        }
    } else {
        u16* dst = vB + (size_t)b * CI_DIM * N_TOK;
#pragma unroll
        for (int m = 0; m < 8; ++m)
#pragma unroll
            for (int r = 0; r < 4; ++r) {
                int o = m * 16 + lg * 4 + r;
                float bia = bias[o];
#pragma unroll
                for (int j = 0; j < 2; ++j)
                    dst[(size_t)o * N_TOK + n0 + cb + j * 16 + li] =
                        f2bf(acc[m][j][r] + bia);
            }
    }
}

// ---------------------------------------------------------------------------
// Kernel B: wave-autonomous MFMA flash attention, KV split 4 ways.
// grid = (32 q-tiles of 128, B, 4), block = 256 (4 indep waves x 32 queries).
// No K/V LDS staging, no barriers: K/V fragments read direct from L2-resident
// global. Only per-wave P tile goes through LDS.
// ---------------------------------------------------------------------------
__global__ __launch_bounds__(256) void attn_mfma_kernel(
    const u16* __restrict__ qT,   // [B][N][CI]
    const u16* __restrict__ kT,   // [B][N][CI]
    const u16* __restrict__ vB,   // [B][CI][N]
    u16* __restrict__ Opart,      // [4][B][N][CI] bf16, unnormalized
    float* __restrict__ Mout,     // [4][B][N]
    float* __restrict__ Lout)     // [4][B][N]
{
    const int qb  = blockIdx.x;
    const int b   = blockIdx.y;
    const int kvh = blockIdx.z;
    const int j_beg = kvh * (N_TOK / KVSPLIT);

    __shared__ u16 Ps[4][32][72];   // per-wave P tile (padded)

    const int t  = threadIdx.x;
    const int w  = t >> 6;
    const int l  = t & 63;
    const int lg = l >> 4;
    const int li = l & 15;
    const int qw = qb * 128 + w * 32;   // this wave's first query row

    const u16* qTb = qT + (size_t)b * N_TOK * CI_DIM;
    const u16* kTb = kT + (size_t)b * N_TOK * CI_DIM;
    const u16* vBb = vB + (size_t)b * CI_DIM * N_TOK;

    // Q fragments direct from global (once)
    bf16x8 qf[2][4];
#pragma unroll
    for (int qt = 0; qt < 2; ++qt)
#pragma unroll
        for (int kc = 0; kc < 4; ++kc)
            qf[qt][kc] = *(const bf16x8*)&qTb[(size_t)(qw + qt * 16 + li) * CI_DIM + kc * 32 + lg * 8];

    f32x4 Oacc[2][8];
#pragma unroll
    for (int qt = 0; qt < 2; ++qt)
#pragma unroll
        for (int ct = 0; ct < 8; ++ct)
#pragma unroll
            for (int r = 0; r < 4; ++r) Oacc[qt][ct][r] = 0.f;

    float mrun[2] = {-1e30f, -1e30f};
    float lrun[2] = {0.f, 0.f};

    for (int it = 0; it < N_TOK / KVSPLIT / 64; ++it) {
        const int j0 = j_beg + it * 64;

        // ---- K fragments direct from global
        bf16x8 ak[4][4];
#pragma unroll
        for (int jt = 0; jt < 4; ++jt)
#pragma unroll
            for (int kc = 0; kc < 4; ++kc)
                ak[jt][kc] = *(const bf16x8*)&kTb[(size_t)(j0 + jt * 16 + li) * CI_DIM + kc * 32 + lg * 8];

        // ---- QK^T (swapped): S^T[j][i]
        f32x4 sacc[2][4];
#pragma unroll
        for (int qt = 0; qt < 2; ++qt)
#pragma unroll
            for (int jt = 0; jt < 4; ++jt)
#pragma unroll
                for (int r = 0; r < 4; ++r) sacc[qt][jt][r] = 0.f;
#pragma unroll
        for (int jt = 0; jt < 4; ++jt)
#pragma unroll
            for (int kc = 0; kc < 4; ++kc) {
                sacc[0][jt] = __builtin_amdgcn_mfma_f32_16x16x32_bf16(ak[jt][kc], qf[0][kc], sacc[0][jt], 0, 0, 0);
                sacc[1][jt] = __builtin_amdgcn_mfma_f32_16x16x32_bf16(ak[jt][kc], qf[1][kc], sacc[1][jt], 0, 0, 0);
            }

        // ---- issue V fragment loads now; latency hides under softmax
        bf16x8 bvf[8][2];
#pragma unroll
        for (int ct = 0; ct < 8; ++ct)
#pragma unroll
            for (int ks = 0; ks < 2; ++ks)
                bvf[ct][ks] = *(const bf16x8*)&vBb[(size_t)(ct * 16 + li) * N_TOK + j0 + ks * 32 + lg * 8];

        // ---- online softmax per query column (col = li; j over lg,reg)
#pragma unroll
        for (int qt = 0; qt < 2; ++qt) {
            float tmax = sacc[qt][0][0];
#pragma unroll
            for (int jt = 0; jt < 4; ++jt)
#pragma unroll
                for (int r = 0; r < 4; ++r) tmax = fmaxf(tmax, sacc[qt][jt][r]);
            tmax = fmaxf(tmax, __shfl_xor(tmax, 16));
            tmax = fmaxf(tmax, __shfl_xor(tmax, 32));

            float mold = mrun[qt];
            float mnew = fmaxf(mold, tmax);
            bool grow = mnew > mold;
            float psum = 0.f;
#pragma unroll
            for (int jt = 0; jt < 4; ++jt) {
                float p0 = __expf(sacc[qt][jt][0] - mnew);
                float p1 = __expf(sacc[qt][jt][1] - mnew);
                float p2 = __expf(sacc[qt][jt][2] - mnew);
                float p3 = __expf(sacc[qt][jt][3] - mnew);
                psum += (p0 + p1) + (p2 + p3);
                u32 lo = cvt_pk_bf16(p0, p1);
                u32 hi = cvt_pk_bf16(p2, p3);
                u64 pk = (u64)lo | ((u64)hi << 32);
                *(u64*)&Ps[w][qt * 16 + li][jt * 16 + lg * 4] = pk;
            }
            psum += __shfl_xor(psum, 16);
            psum += __shfl_xor(psum, 32);

            if (__any(grow)) {
                float scale = __expf(mold - mnew);
                lrun[qt] = lrun[qt] * scale + psum;
                mrun[qt] = mnew;
#pragma unroll
                for (int r = 0; r < 4; ++r) {
                    float sc_r = __shfl(scale, lg * 4 + r);
#pragma unroll
                    for (int ct = 0; ct < 8; ++ct) Oacc[qt][ct][r] *= sc_r;
                }
            } else {
                lrun[qt] += psum;
            }
        }

        // ---- PV: O^T[i][c] += P[i][j] * V^T[j][c]
#pragma unroll
        for (int ks = 0; ks < 2; ++ks) {
            bf16x8 ap0 = *(const bf16x8*)&Ps[w][li][ks * 32 + lg * 8];
            bf16x8 ap1 = *(const bf16x8*)&Ps[w][16 + li][ks * 32 + lg * 8];
#pragma unroll
            for (int ct = 0; ct < 8; ++ct) {
                Oacc[0][ct] = __builtin_amdgcn_mfma_f32_16x16x32_bf16(ap0, bvf[ct][ks], Oacc[0][ct], 0, 0, 0);
                Oacc[1][ct] = __builtin_amdgcn_mfma_f32_16x16x32_bf16(ap1, bvf[ct][ks], Oacc[1][ct], 0, 0, 0);
            }
        }
    }

    // ---- epilogue: m/l + unnormalized bf16 O partial
    const size_t mlbase = ((size_t)kvh * B_DIM + b) * N_TOK + qw;
    if (lg == 0) {
#pragma unroll
        for (int qt = 0; qt < 2; ++qt) {
            Mout[mlbase + qt * 16 + li] = mrun[qt];
            Lout[mlbase + qt * 16 + li] = lrun[qt];
        }
    }
    u16* Ob = Opart + mlbase * CI_DIM;
#pragma unroll
    for (int qt = 0; qt < 2; ++qt)
#pragma unroll
        for (int ct = 0; ct < 8; ++ct)
#pragma unroll
            for (int r = 0; r < 4; ++r)
                Ob[(size_t)(qt * 16 + lg * 4 + r) * CI_DIM + ct * 16 + li] =
                    f2bf(Oacc[qt][ct][r]);
}

// ---------------------------------------------------------------------------
// Kernel C: merge the 4 KV-quarter partials -> attnoB bf16 [B][N][CI]
// grid = (64 q-tiles of 64, B), block = 256
// ---------------------------------------------------------------------------
__global__ __launch_bounds__(256) void attn_merge_kernel(
    const u16* __restrict__ Opart, const float* __restrict__ Mout,
    const float* __restrict__ Lout, u16* __restrict__ attnoB)
{
    const int qb = blockIdx.x;
    const int b  = blockIdx.y;
    const int t  = threadIdx.x;
    const int i  = qb * 64 + (t & 63);
    const int c0 = (t >> 6) * 32;

    size_t ns[KVSPLIT];
    float cs[KVSPLIT];
    float m = -1e30f;
#pragma unroll
    for (int s = 0; s < KVSPLIT; ++s) {
        ns[s] = ((size_t)s * B_DIM + b) * N_TOK + i;
        cs[s] = Mout[ns[s]];
        m = fmaxf(m, cs[s]);
    }
    float den = 0.f;
#pragma unroll
    for (int s = 0; s < KVSPLIT; ++s) {
        cs[s] = __expf(cs[s] - m);
        den += Lout[ns[s]] * cs[s];
    }
    float inv = 1.f / den;
#pragma unroll
    for (int s = 0; s < KVSPLIT; ++s) cs[s] *= inv;

    u16* ab = attnoB + ((size_t)b * N_TOK + i) * CI_DIM;
#pragma unroll
    for (int g = 0; g < 4; ++g) {
        float acc[8];
#pragma unroll
        for (int e = 0; e < 8; ++e) acc[e] = 0.f;
#pragma unroll
        for (int s = 0; s < KVSPLIT; ++s) {
            u16x8 ov = *(const u16x8*)&Opart[ns[s] * CI_DIM + c0 + g * 8];
#pragma unroll
            for (int e = 0; e < 8; ++e) acc[e] += bf2f(ov[e]) * cs[s];
        }
        u16x8 res;
#pragma unroll
        for (int e = 0; e < 8; ++e) res[e] = f2bf(acc[e]);
        *(u16x8*)&ab[c0 + g * 8] = res;
    }
}

// ---------------------------------------------------------------------------
// Kernel D: output projection via MFMA + bias + residual, fp32 out.
// ---------------------------------------------------------------------------
__global__ __launch_bounds__(256) void out_gemm_kernel(
    const u16* __restrict__ attnoB,  // [B][N][CI] bf16
    const u16* __restrict__ woB,     // [C][CI] bf16
    const float* __restrict__ bo,    // [C]
    const float* __restrict__ x,     // [B][C][N]
    float* __restrict__ out)         // [B][C][N]
{
    const int n0 = blockIdx.x * 64;
    const int b  = blockIdx.y;
    const int t  = threadIdx.x;
    const int w  = t >> 6;
    const int l  = t & 63;
    const int lg = l >> 4;
    const int li = l & 15;
    const int co0 = w * 128;

    const u16* ab = attnoB + (size_t)b * N_TOK * CI_DIM;

    f32x4 acc[8][4];
#pragma unroll
    for (int m = 0; m < 8; ++m)
#pragma unroll
        for (int j = 0; j < 4; ++j)
#pragma unroll
            for (int r = 0; r < 4; ++r) acc[m][j][r] = 0.f;

    const u16* Abase = woB + (size_t)(co0 + li) * CI_DIM + lg * 8;
    const u16* Bbase = ab + (size_t)(n0 + li) * CI_DIM + lg * 8;

#pragma unroll
    for (int kk = 0; kk < 4; ++kk) {
        bf16x8 af[8], bfv[4];
#pragma unroll
        for (int m = 0; m < 8; ++m)
            af[m] = *(const bf16x8*)&Abase[(size_t)(m * 16) * CI_DIM + kk * 32];
#pragma unroll
        for (int j = 0; j < 4; ++j)
            bfv[j] = *(const bf16x8*)&Bbase[(size_t)(j * 16) * CI_DIM + kk * 32];
#pragma unroll
        for (int m = 0; m < 8; ++m)
#pragma unroll
            for (int j = 0; j < 4; ++j)
                acc[m][j] = __builtin_amdgcn_mfma_f32_16x16x32_bf16(
                    af[m], bfv[j], acc[m][j], 0, 0, 0);
    }

    const size_t base = (size_t)b * C_DIM * N_TOK;
#pragma unroll
    for (int m = 0; m < 8; ++m)
#pragma unroll
        for (int r = 0; r < 4; ++r) {
            int co = co0 + m * 16 + lg * 4 + r;
            float bia = bo[co];
#pragma unroll
            for (int j = 0; j < 4; ++j) {
                size_t idx = base + (size_t)co * N_TOK + n0 + j * 16 + li;
                out[idx] = acc[m][j][r] + bia + x[idx];
            }
        }
}

extern "C" void kernel_launch(void* const* d_in, const int* in_sizes, int n_in,
                              void* d_out, int out_size, void* d_ws, size_t ws_size,
                              hipStream_t stream) {
    const float* x  = (const float*)d_in[0];
    const float* wq = (const float*)d_in[1];
    const float* bq = (const float*)d_in[2];
    const float* wk = (const float*)d_in[3];
    const float* bk = (const float*)d_in[4];
    const float* wv = (const float*)d_in[5];
    const float* bv = (const float*)d_in[6];
    const float* wo = (const float*)d_in[7];
    const float* bo = (const float*)d_in[8];
    float* out = (float*)d_out;

    // workspace layout (bytes):
    //  [0,16M)         xT bf16 [B][N][C]  -- dead after qkv_gemm; reused as
    //                  Opart bf16 [4][B][N][CI] (exactly 16 MB)
    //  [16M,16.5M)     wqB/wkB/wvB/woB bf16 (128K each)
    //  [16.5M,20.5M)   qT bf16 [B][N][CI]
    //  [20.5M,24.5M)   kT bf16 [B][N][CI]
    //  [24.5M,28.5M)   vB bf16 [B][CI][N]
    //  [28.5M,+512K)   Mout/Lout f32 [4][B][N] (256K each)
    //  [29M,33M)       attnoB bf16 [B][N][CI]
    char* ws = (char*)d_ws;
    const size_t MB = 1024 * 1024;
    u16*   xT    = (u16*)(ws);
    u16*   Opart = (u16*)(ws);                   // aliases xT (16 MB, exact)
    u16*   wqB   = (u16*)(ws + 16 * MB);
    u16*   wkB   = (u16*)(ws + 16 * MB + 128 * 1024);
    u16*   wvB   = (u16*)(ws + 16 * MB + 256 * 1024);
    u16*   woB   = (u16*)(ws + 16 * MB + 384 * 1024);
    u16*   qT    = (u16*)(ws + 16 * MB + 512 * 1024);
    u16*   kT    = (u16*)(ws + 20 * MB + 512 * 1024);
    u16*   vB    = (u16*)(ws + 24 * MB + 512 * 1024);
    float* Mout  = (float*)(ws + 28 * MB + 512 * 1024);
    float* Lout  = (float*)(ws + 28 * MB + 768 * 1024);
    u16*  attnoB = (u16*)(ws + 29 * MB);

    xpose_kernel<<<dim3(64, 8, 4), 256, 0, stream>>>(x, xT);
    wconv_kernel<<<dim3(32, 4), 256, 0, stream>>>(
        wq, wk, wv, wo, wqB, wkB, wvB, woB);
    qkv_gemm_kernel<<<dim3(32, 4, 3), 256, 0, stream>>>(
        xT, wqB, wkB, wvB, bq, bk, bv, qT, kT, vB);
    attn_mfma_kernel<<<dim3(32, 4, KVSPLIT), 256, 0, stream>>>(
        qT, kT, vB, Opart, Mout, Lout);
    attn_merge_kernel<<<dim3(64, 4), 256, 0, stream>>>(
        Opart, Mout, Lout, attnoB);
    out_gemm_kernel<<<dim3(64, 4), 256, 0, stream>>>(
        attnoB, woB, bo, x, out);
}